// Round 1
// 317.943 us; speedup vs baseline: 1.1305x; 1.1305x over previous
//
#include <hip/hip_runtime.h>
#include <hip/hip_bf16.h>
#include <math.h>

// B=128 rows, D=512*512=262144. dots[i][j]=Z[i]·Y[j]; sim[a][b]=dots[b][a]/
// max(xn[b]*yn[a],eps); outputs top1/top10 retrieval accuracy.
//
// R6: counters showed nothing saturated (Mfma 6%, VALU 9%, HBM 16%, Occ 26%)
// -> stall-bound. Restructure for latency hiding, same split-bf16 numerics:
//   * 512-thread (8-wave) blocks: acc 64->32 regs, staging 8->4 float4/thread
//   * true 2-tile-deep register prefetch (A/B buffers, window = 2 iterations)
//   * norms in registers + shuffle epilogue (no in-loop LDS atomics)
//   * grid 512 = exactly 2 blocks/CU (16 waves/CU), no tail; partials 32 MiB
// mfma_f32_16x16x32_bf16, doc-verified layouts (m89/m91/m92):
//   A: m=lane&15, k=(lane>>4)*8+j ; C/D: col=lane&15, row=(lane>>4)*4+reg.

#define DIMD 262144

typedef short  bf16x8  __attribute__((ext_vector_type(8)));   // 8 bf16 = 4 VGPR
typedef float  floatx4 __attribute__((ext_vector_type(4)));   // C/D frag

union FragU { uint4 u; bf16x8 v; };

// ---------------- main: split-bf16 MFMA GEMM, split-K partials ---------------
// grid nb blocks x 512 thr (8 waves). Block owns orig-K chunk of NT*32.
// LDS planes: [0]=Z_hi [1]=Z_lo [2]=Y_hi [3]=Y_lo, 128 rows x 32 k (bf16),
// row stride 40 ushorts = 80 B (20-bank rotation -> 2-way, free).
__global__ __launch_bounds__(512, 4)
void mfma_dot_kernel(const float* __restrict__ Z, const float* __restrict__ Y,
                     float* __restrict__ partials, float* __restrict__ norms,
                     int NT) {
    __shared__ __align__(16) ushort planes[4][128][40];  // 40960 B exactly

    const int tid = threadIdx.x;
    const int lid = tid & 63;
    const int w   = tid >> 6;          // 0..7

    // staging: thread -> rows {srow, srow+64}, float4 q within 32-k tile
    const int srow = tid >> 3;         // 0..63
    const int q    = tid & 7;          // 0..7

    // mfma: wave w owns C rows [m0,m0+64) x cols [n0,n0+32)
    const int m0 = 64 * (w >> 2);
    const int n0 = 32 * (w & 3);
    const int fr = lid & 15;           // fragment row (m or n)
    const int fk = (lid >> 4) * 8;     // k offset in ushorts

    floatx4 acc[4][2];
#pragma unroll
    for (int a = 0; a < 4; ++a)
#pragma unroll
        for (int b = 0; b < 2; ++b)
            acc[a][b] = (floatx4){0.f, 0.f, 0.f, 0.f};

    float z2[2] = {0.f, 0.f}, y2[2] = {0.f, 0.f};   // norm partials, in regs

    const uint kbase = (uint)blockIdx.x * (uint)(NT * 32);
    const uint off0  = (uint)srow * (uint)DIMD + kbase + 4u * (uint)q;
    const uint off1  = off0 + 64u * (uint)DIMD;   // max ~33.5M elems < 2^32

    // 2-deep prefetch buffers: A = even tiles, B = odd tiles (static indexing)
    float4 za[2], ya[2], zb[2], yb[2];
    za[0] = *(const float4*)(Z + off0);      za[1] = *(const float4*)(Z + off1);
    ya[0] = *(const float4*)(Y + off0);      ya[1] = *(const float4*)(Y + off1);
    zb[0] = *(const float4*)(Z + off0 + 32); zb[1] = *(const float4*)(Z + off1 + 32);
    yb[0] = *(const float4*)(Y + off0 + 32); yb[1] = *(const float4*)(Y + off1 + 32);

    // fp32 -> (hi,lo) bf16 truncation split, store planes, norm accumulate
    auto convstore = [&](const float4 (&zr)[2], const float4 (&yr)[2]) {
#pragma unroll
        for (int i = 0; i < 2; ++i) {
            const int row = srow + 64 * i;
            {
                const float4 v = zr[i];
                const uint h0 = __float_as_uint(v.x) >> 16, h1 = __float_as_uint(v.y) >> 16;
                const uint h2 = __float_as_uint(v.z) >> 16, h3 = __float_as_uint(v.w) >> 16;
                const uint l0 = __float_as_uint(v.x - __uint_as_float(h0 << 16)) >> 16;
                const uint l1 = __float_as_uint(v.y - __uint_as_float(h1 << 16)) >> 16;
                const uint l2 = __float_as_uint(v.z - __uint_as_float(h2 << 16)) >> 16;
                const uint l3 = __float_as_uint(v.w - __uint_as_float(h3 << 16)) >> 16;
                *(uint2*)&planes[0][row][4 * q] =
                    make_uint2(h0 | (h1 << 16), h2 | (h3 << 16));
                *(uint2*)&planes[1][row][4 * q] =
                    make_uint2(l0 | (l1 << 16), l2 | (l3 << 16));
                z2[i] += v.x * v.x + v.y * v.y + v.z * v.z + v.w * v.w;
            }
            {
                const float4 v = yr[i];
                const uint h0 = __float_as_uint(v.x) >> 16, h1 = __float_as_uint(v.y) >> 16;
                const uint h2 = __float_as_uint(v.z) >> 16, h3 = __float_as_uint(v.w) >> 16;
                const uint l0 = __float_as_uint(v.x - __uint_as_float(h0 << 16)) >> 16;
                const uint l1 = __float_as_uint(v.y - __uint_as_float(h1 << 16)) >> 16;
                const uint l2 = __float_as_uint(v.z - __uint_as_float(h2 << 16)) >> 16;
                const uint l3 = __float_as_uint(v.w - __uint_as_float(h3 << 16)) >> 16;
                *(uint2*)&planes[2][row][4 * q] =
                    make_uint2(h0 | (h1 << 16), h2 | (h3 << 16));
                *(uint2*)&planes[3][row][4 * q] =
                    make_uint2(l0 | (l1 << 16), l2 | (l3 << 16));
                y2[i] += v.x * v.x + v.y * v.y + v.z * v.z + v.w * v.w;
            }
        }
    };

    // fragments + 24 MFMAs (4x2 C tiles x 3 products)
    auto mfma_phase = [&]() {
        FragU bh[2], bl[2];
#pragma unroll
        for (int tn = 0; tn < 2; ++tn) {
            bh[tn].u = *(const uint4*)&planes[2][n0 + 16 * tn + fr][fk];
            bl[tn].u = *(const uint4*)&planes[3][n0 + 16 * tn + fr][fk];
        }
#pragma unroll
        for (int tm = 0; tm < 4; ++tm) {
            FragU ah, al;
            ah.u = *(const uint4*)&planes[0][m0 + 16 * tm + fr][fk];
            al.u = *(const uint4*)&planes[1][m0 + 16 * tm + fr][fk];
#pragma unroll
            for (int tn = 0; tn < 2; ++tn) {
                acc[tm][tn] = __builtin_amdgcn_mfma_f32_16x16x32_bf16(ah.v, bh[tn].v, acc[tm][tn], 0, 0, 0);
                acc[tm][tn] = __builtin_amdgcn_mfma_f32_16x16x32_bf16(ah.v, bl[tn].v, acc[tm][tn], 0, 0, 0);
                acc[tm][tn] = __builtin_amdgcn_mfma_f32_16x16x32_bf16(al.v, bh[tn].v, acc[tm][tn], 0, 0, 0);
            }
        }
    };

    // NT is even (16 for nb=512, 32 for nb=256); A/B ping-pong, loads for
    // tile t+2 issued the moment buffer t is consumed -> ~2 iterations in flight.
#pragma unroll 1
    for (int t = 0; t < NT; t += 2) {
        __syncthreads();               // prev odd tile's LDS readers done
        convstore(za, ya);
        if (t + 2 < NT) {
            const uint ko = (uint)(t + 2) * 32u;
            za[0] = *(const float4*)(Z + off0 + ko); za[1] = *(const float4*)(Z + off1 + ko);
            ya[0] = *(const float4*)(Y + off0 + ko); ya[1] = *(const float4*)(Y + off1 + ko);
        }
        __syncthreads();               // planes ready
        mfma_phase();

        __syncthreads();
        convstore(zb, yb);
        if (t + 3 < NT) {
            const uint ko = (uint)(t + 3) * 32u;
            zb[0] = *(const float4*)(Z + off0 + ko); zb[1] = *(const float4*)(Z + off1 + ko);
            yb[0] = *(const float4*)(Y + off0 + ko); yb[1] = *(const float4*)(Y + off1 + ko);
        }
        __syncthreads();
        mfma_phase();
    }

    // ---- norms: reduce the 8 q-lanes of each row in-wave, one atomic per row
#pragma unroll
    for (int m = 1; m <= 4; m <<= 1) {
        z2[0] += __shfl_xor(z2[0], m); z2[1] += __shfl_xor(z2[1], m);
        y2[0] += __shfl_xor(y2[0], m); y2[1] += __shfl_xor(y2[1], m);
    }
    if (q == 0) {
        atomicAdd(&norms[srow],            z2[0]);
        atomicAdd(&norms[srow + 64],       z2[1]);
        atomicAdd(&norms[128 + srow],      y2[0]);
        atomicAdd(&norms[128 + srow + 64], y2[1]);
    }

    // partial C tile: C/D layout col=lane&15, row=(lane>>4)*4+reg
    float* P = partials + (size_t)blockIdx.x * 16384;
    const int rq = (lid >> 4) * 4;
#pragma unroll
    for (int tm = 0; tm < 4; ++tm)
#pragma unroll
        for (int tn = 0; tn < 2; ++tn)
#pragma unroll
            for (int r = 0; r < 4; ++r)
                P[(size_t)(m0 + 16 * tm + rq + r) * 128 + (n0 + 16 * tn + fr)] =
                    acc[tm][tn][r];
}

// ---------------- fallback: fp32 atomic-combine (tiny ws only) ---------------
#define BK   16
#define LSTR 132
__global__ __launch_bounds__(256)
void dot_norm_atomic(const float* __restrict__ Z, const float* __restrict__ Y,
                     float* __restrict__ dots, float* __restrict__ norms,
                     int KC) {
    __shared__ float lA[BK][LSTR];
    __shared__ float lB[BK][LSTR];
    const int tid = threadIdx.x;
    const int tx = tid & 15, ty = tid >> 4;
    const int r0 = ty * 8, c0 = tx * 8;
    const int rowm = tid >> 2, kq = tid & 3;
    float acc[8][8];
#pragma unroll
    for (int i = 0; i < 8; ++i)
#pragma unroll
        for (int j = 0; j < 8; ++j) acc[i][j] = 0.f;
    float a2s0 = 0.f, a2s1 = 0.f, b2s0 = 0.f, b2s1 = 0.f;
    const size_t kbase = (size_t)blockIdx.x * KC;
    const size_t offA0 = (size_t)rowm * DIMD + kbase + kq * 4;
    const size_t offA1 = (size_t)(rowm + 64) * DIMD + kbase + kq * 4;
    const int niter = KC / BK;
#pragma unroll 1
    for (int t = 0; t < niter; ++t) {
        const size_t ko = (size_t)t * BK;
        const float4 av0 = *(const float4*)(Z + offA0 + ko);
        const float4 av1 = *(const float4*)(Z + offA1 + ko);
        const float4 bv0 = *(const float4*)(Y + offA0 + ko);
        const float4 bv1 = *(const float4*)(Y + offA1 + ko);
        a2s0 += av0.x*av0.x + av0.y*av0.y + av0.z*av0.z + av0.w*av0.w;
        a2s1 += av1.x*av1.x + av1.y*av1.y + av1.z*av1.z + av1.w*av1.w;
        b2s0 += bv0.x*bv0.x + bv0.y*bv0.y + bv0.z*bv0.z + bv0.w*bv0.w;
        b2s1 += bv1.x*bv1.x + bv1.y*bv1.y + bv1.z*bv1.z + bv1.w*bv1.w;
        __syncthreads();
        const int kk = kq * 4;
        lA[kk+0][rowm]    = av0.x; lA[kk+1][rowm]    = av0.y;
        lA[kk+2][rowm]    = av0.z; lA[kk+3][rowm]    = av0.w;
        lA[kk+0][rowm+64] = av1.x; lA[kk+1][rowm+64] = av1.y;
        lA[kk+2][rowm+64] = av1.z; lA[kk+3][rowm+64] = av1.w;
        lB[kk+0][rowm]    = bv0.x; lB[kk+1][rowm]    = bv0.y;
        lB[kk+2][rowm]    = bv0.z; lB[kk+3][rowm]    = bv0.w;
        lB[kk+0][rowm+64] = bv1.x; lB[kk+1][rowm+64] = bv1.y;
        lB[kk+2][rowm+64] = bv1.z; lB[kk+3][rowm+64] = bv1.w;
        __syncthreads();
#pragma unroll
        for (int k = 0; k < BK; ++k) {
            const float4 a0 = *(const float4*)&lA[k][r0];
            const float4 a1 = *(const float4*)&lA[k][r0 + 4];
            const float4 b0 = *(const float4*)&lB[k][c0];
            const float4 b1 = *(const float4*)&lB[k][c0 + 4];
            const float a[8] = {a0.x,a0.y,a0.z,a0.w,a1.x,a1.y,a1.z,a1.w};
            const float b[8] = {b0.x,b0.y,b0.z,b0.w,b1.x,b1.y,b1.z,b1.w};
#pragma unroll
            for (int i = 0; i < 8; ++i)
#pragma unroll
                for (int j = 0; j < 8; ++j)
                    acc[i][j] = fmaf(a[i], b[j], acc[i][j]);
        }
    }
    __syncthreads();
    float* nrm = &lA[0][0];
    nrm[tid] = 0.f;
    __syncthreads();
    atomicAdd(&nrm[rowm],            a2s0);
    atomicAdd(&nrm[rowm + 64],       a2s1);
    atomicAdd(&nrm[128 + rowm],      b2s0);
    atomicAdd(&nrm[128 + rowm + 64], b2s1);
    __syncthreads();
    atomicAdd(&norms[tid], nrm[tid]);
#pragma unroll
    for (int i = 0; i < 8; ++i)
#pragma unroll
        for (int j = 0; j < 8; ++j)
            atomicAdd(&dots[(size_t)(r0 + i) * 128 + (c0 + j)], acc[i][j]);
}

// ---------------- reduce stage 1: nb partials -> 32 chunk-sums ---------------
__global__ __launch_bounds__(256)
void reduce_stage1(const float* __restrict__ partials, float* __restrict__ stage,
                   int per_chunk) {
    const int g = blockIdx.x * 256 + threadIdx.x;   // 512 blocks -> 131072
    const int f4 = g & 4095;
    const int chunk = g >> 12;
    const float4* p = (const float4*)partials;
    float4 s = make_float4(0.f, 0.f, 0.f, 0.f);
    const size_t base = (size_t)chunk * per_chunk;
    for (int k = 0; k < per_chunk; ++k) {
        const float4 v = p[(base + k) * 4096 + f4];
        s.x += v.x; s.y += v.y; s.z += v.z; s.w += v.w;
    }
    ((float4*)stage)[(size_t)chunk * 4096 + f4] = s;
}

// ---------------- rank: fused chunk-sum + sim + top1/top10 -------------------
// block a = sim row (Y index), thread b = col (Z index). out must be pre-zeroed.
__global__ __launch_bounds__(128)
void rank_kernel(const float* __restrict__ stage, const float* __restrict__ norms,
                 float* __restrict__ out, int nchunks) {
    __shared__ float sim[128];
    __shared__ int cnt;
    const int a = blockIdx.x;
    const int b = threadIdx.x;
    float s = 0.f;
    for (int c = 0; c < nchunks; ++c)
        s += stage[(size_t)c * 16384 + (size_t)b * 128 + a];
    const float v = s / fmaxf(sqrtf(norms[b]) * sqrtf(norms[128 + a]), 1e-8f);
    sim[b] = v;
    if (b == 0) cnt = 0;
    __syncthreads();
    const float diag = sim[a];
    if (b != a && v > diag) atomicAdd(&cnt, 1);
    __syncthreads();
    if (b == 0) {
        if (cnt == 0) atomicAdd(&out[0], 1.0f / 128.0f);   // k/128 exact in fp32
        if (cnt < 10) atomicAdd(&out[1], 1.0f / 128.0f);
    }
}

extern "C" void kernel_launch(void* const* d_in, const int* in_sizes, int n_in,
                              void* d_out, int out_size, void* d_ws, size_t ws_size,
                              hipStream_t stream) {
    const float* Z = (const float*)d_in[0];
    const float* Y = (const float*)d_in[1];
    float* dots     = (float*)d_ws;            // 16384 (fallback only)
    float* norms    = dots + 128 * 128;        // 256
    float* stage    = norms + 256;             // 32*16384
    float* partials = stage + 32 * 16384;      // nb*16384
    float* out      = (float*)d_out;

    const size_t head_floats = 128 * 128 + 256 + 32 * 16384;
    int nb = 0;
    const int cands[2] = {512, 256};
    for (int c = 0; c < 2; ++c) {
        if ((head_floats + (size_t)cands[c] * 16384) * sizeof(float) <= ws_size) {
            nb = cands[c];
            break;
        }
    }

    hipMemsetAsync(d_ws, 0, (128 * 128 + 256) * sizeof(float), stream);
    hipMemsetAsync(d_out, 0, 2 * sizeof(float), stream);

    if (nb > 0) {
        mfma_dot_kernel<<<nb, 512, 0, stream>>>(Z, Y, partials, norms,
                                                DIMD / nb / 32);
        reduce_stage1<<<512, 256, 0, stream>>>(partials, stage, nb / 32);
        rank_kernel<<<128, 128, 0, stream>>>(stage, norms, out, 32);
    } else {
        dot_norm_atomic<<<512, 256, 0, stream>>>(Z, Y, dots, norms, DIMD / 512);
        rank_kernel<<<128, 128, 0, stream>>>(dots, norms, out, 1);
    }
}

// Round 2
// 313.092 us; speedup vs baseline: 1.1480x; 1.0155x over previous
//
#include <hip/hip_runtime.h>
#include <hip/hip_bf16.h>
#include <math.h>

// B=128 rows, D=512*512=262144. dots[i][j]=Z[i]·Y[j]; sim[a][b]=dots[b][a]/
// max(xn[b]*yn[a],eps); outputs top1/top10 retrieval accuracy.
//
// R7: R6 post-mortem — VGPR_Count=64 proves the compiler SANK the register
// prefetch loads to their use points (can't fit 4 float4 buffers + frags in
// 64 VGPRs), so every tile exposed full HBM latency under a barrier.
// Fix: stage via __builtin_amdgcn_global_load_lds (un-sinkable, zero data
// VGPRs), fp32 in LDS, hi/lo bf16 split done at fragment-read time.
//   * linear LDS dest required -> XOR chunk swizzle (c ^= row&7) applied to
//     the GLOBAL source address per lane and to every LDS read (rule #21).
//   * minimum 2-phase pipeline: STAGE(buf^1,t+1) -> compute(buf) -> 1 barrier.
//   * norms read back from LDS (per-thread fixed 16-float slice per tile).
// mfma_f32_16x16x32_bf16, doc-verified layouts (m89/m91/m92):
//   A: m=lane&15, k=(lane>>4)*8+j ; C/D: col=lane&15, row=(lane>>4)*4+reg.

#define DIMD 262144

typedef short  bf16x8  __attribute__((ext_vector_type(8)));   // 8 bf16 = 4 VGPR
typedef float  floatx4 __attribute__((ext_vector_type(4)));   // C/D frag

union FragU { uint4 u; bf16x8 v; };

#define GLOAD_LDS16(g, l)                                        \
    __builtin_amdgcn_global_load_lds(                            \
        (const __attribute__((address_space(1))) void*)(g),      \
        (__attribute__((address_space(3))) void*)(l), 16, 0, 0)

// fp32x8 -> (hi,lo) bf16x8 truncation split (identical numerics to R5/R6)
static __device__ __forceinline__ void cvt_hilo(const float4 f0, const float4 f1,
                                                bf16x8& hv, bf16x8& lv) {
    const float ff[8] = {f0.x, f0.y, f0.z, f0.w, f1.x, f1.y, f1.z, f1.w};
    uint hu[4], lu[4];
#pragma unroll
    for (int j = 0; j < 4; ++j) {
        const uint b0  = __float_as_uint(ff[2 * j]);
        const uint b1  = __float_as_uint(ff[2 * j + 1]);
        const uint hf0 = b0 & 0xffff0000u;
        const uint hf1 = b1 & 0xffff0000u;
        hu[j] = (b0 >> 16) | hf1;                       // h0 | h1<<16
        const uint lo0 = __float_as_uint(ff[2 * j]     - __uint_as_float(hf0));
        const uint lo1 = __float_as_uint(ff[2 * j + 1] - __uint_as_float(hf1));
        lu[j] = (lo0 >> 16) | (lo1 & 0xffff0000u);      // l0 | l1<<16
    }
    FragU h, l;
    h.u = make_uint4(hu[0], hu[1], hu[2], hu[3]);
    l.u = make_uint4(lu[0], lu[1], lu[2], lu[3]);
    hv = h.v; lv = l.v;
}

// ---------------- main: split-bf16 MFMA GEMM, split-K partials ---------------
// grid nb blocks x 512 thr (8 waves). Block owns orig-K chunk of NT*32.
// LDS: lds[buf][mat][128 rows][32 floats], row stride 128 B, 16B chunks
// swizzled: LDS(r,c) holds global chunk (r, c ^ (r&7)).
__global__ __launch_bounds__(512, 4)
void mfma_dot_kernel(const float* __restrict__ Z, const float* __restrict__ Y,
                     float* __restrict__ partials, float* __restrict__ norms,
                     int NT) {
    __shared__ __align__(16) float ldsf[2][2][128][32];   // 65536 B

    const int tid = threadIdx.x;
    const int lid = tid & 63;
    const int w   = tid >> 6;          // 0..7

    // mfma: wave w owns C rows [m0,m0+64) x cols [n0,n0+32)
    const int m0  = 64 * (w >> 2);
    const int n0  = 32 * (w & 3);
    const int fr  = lid & 15;          // fragment row (m or n)
    const int fkc = (lid >> 4) * 2;    // fragment k chunk (0,2,4,6)

    floatx4 acc[4][2];
#pragma unroll
    for (int a = 0; a < 4; ++a)
#pragma unroll
        for (int b = 0; b < 2; ++b)
            acc[a][b] = (floatx4){0.f, 0.f, 0.f, 0.f};

    // ---- staging geometry: wave w stages rows [16w,16w+16) of both matrices.
    // lane l -> row 16w + 8*(win) + (l>>3), chunk_src = (l&7)^(l>>3) (swizzle).
    const size_t kbase = (size_t)blockIdx.x * ((size_t)NT * 32);
    const int    w16   = 16 * w;
    const int    csrc  = ((lid & 7) ^ (lid >> 3)) * 4;   // float offset in row
    const size_t g0    = (size_t)(w16 + (lid >> 3)) * DIMD + kbase + csrc;
    const size_t g1    = g0 + 8ull * DIMD;

    auto stage = [&](int b, size_t ko) {
        GLOAD_LDS16(Z + g0 + ko, &ldsf[b][0][w16][0]);
        GLOAD_LDS16(Z + g1 + ko, &ldsf[b][0][w16 + 8][0]);
        GLOAD_LDS16(Y + g0 + ko, &ldsf[b][1][w16][0]);
        GLOAD_LDS16(Y + g1 + ko, &ldsf[b][1][w16 + 8][0]);
    };

    // ---- norm slice: thread covers (mat, row, half) ; 16 floats per tile
    const int nmat = tid >> 8;             // 0 = Z, 1 = Y
    const int nrow = (tid >> 1) & 127;
    const int nh4  = (tid & 1) * 4;        // chunk base 0 or 4
    const int nsw  = nrow & 7;
    float nsum = 0.f;

    stage(0, 0);
    __syncthreads();                       // buf0 resident (vmcnt drained here)

#pragma unroll 1
    for (int t = 0; t < NT; ++t) {
        const int b = t & 1;
        if (t + 1 < NT) stage(b ^ 1, (size_t)(t + 1) * 32);

        // ---- fragments (read fp32 + convert) + 24 MFMAs (4x2 tiles x 3)
        FragU dummy;
        bf16x8 bh[2], bl[2];
#pragma unroll
        for (int tn = 0; tn < 2; ++tn) {
            const int r = n0 + 16 * tn + fr;
            const int s = r & 7;
            const float* rp = &ldsf[b][1][r][0];
            const float4 f0 = *(const float4*)(rp + ((fkc ^ s) * 4));
            const float4 f1 = *(const float4*)(rp + (((fkc + 1) ^ s) * 4));
            cvt_hilo(f0, f1, bh[tn], bl[tn]);
        }
#pragma unroll
        for (int tm = 0; tm < 4; ++tm) {
            const int r = m0 + 16 * tm + fr;
            const int s = r & 7;
            const float* rp = &ldsf[b][0][r][0];
            const float4 f0 = *(const float4*)(rp + ((fkc ^ s) * 4));
            const float4 f1 = *(const float4*)(rp + (((fkc + 1) ^ s) * 4));
            bf16x8 ah, al;
            cvt_hilo(f0, f1, ah, al);
#pragma unroll
            for (int tn = 0; tn < 2; ++tn) {
                acc[tm][tn] = __builtin_amdgcn_mfma_f32_16x16x32_bf16(ah, bh[tn], acc[tm][tn], 0, 0, 0);
                acc[tm][tn] = __builtin_amdgcn_mfma_f32_16x16x32_bf16(ah, bl[tn], acc[tm][tn], 0, 0, 0);
                acc[tm][tn] = __builtin_amdgcn_mfma_f32_16x16x32_bf16(al, bh[tn], acc[tm][tn], 0, 0, 0);
            }
        }

        // ---- norm accumulation from LDS (each element exactly once per block)
        {
            const float* rp = &ldsf[b][nmat][nrow][0];
#pragma unroll
            for (int j = 0; j < 4; ++j) {
                const float4 v = *(const float4*)(rp + (((nh4 + j) ^ nsw) * 4));
                nsum += v.x * v.x + v.y * v.y + v.z * v.z + v.w * v.w;
            }
        }

        __syncthreads();   // t+1 loads landed (vmcnt drain) + buf b readers done
    }

    // ---- norms: combine the two half-threads, one atomic per (mat,row)
    nsum += __shfl_xor(nsum, 1);
    if ((tid & 1) == 0) atomicAdd(&norms[nmat * 128 + nrow], nsum);

    // partial C tile: C/D layout col=lane&15, row=(lane>>4)*4+reg
    float* P = partials + (size_t)blockIdx.x * 16384;
    const int rq = (lid >> 4) * 4;
#pragma unroll
    for (int tm = 0; tm < 4; ++tm)
#pragma unroll
        for (int tn = 0; tn < 2; ++tn)
#pragma unroll
            for (int r = 0; r < 4; ++r)
                P[(size_t)(m0 + 16 * tm + rq + r) * 128 + (n0 + 16 * tn + fr)] =
                    acc[tm][tn][r];
}

// ---------------- fallback: fp32 atomic-combine (tiny ws only) ---------------
#define BK   16
#define LSTR 132
__global__ __launch_bounds__(256)
void dot_norm_atomic(const float* __restrict__ Z, const float* __restrict__ Y,
                     float* __restrict__ dots, float* __restrict__ norms,
                     int KC) {
    __shared__ float lA[BK][LSTR];
    __shared__ float lB[BK][LSTR];
    const int tid = threadIdx.x;
    const int tx = tid & 15, ty = tid >> 4;
    const int r0 = ty * 8, c0 = tx * 8;
    const int rowm = tid >> 2, kq = tid & 3;
    float acc[8][8];
#pragma unroll
    for (int i = 0; i < 8; ++i)
#pragma unroll
        for (int j = 0; j < 8; ++j) acc[i][j] = 0.f;
    float a2s0 = 0.f, a2s1 = 0.f, b2s0 = 0.f, b2s1 = 0.f;
    const size_t kbase = (size_t)blockIdx.x * KC;
    const size_t offA0 = (size_t)rowm * DIMD + kbase + kq * 4;
    const size_t offA1 = (size_t)(rowm + 64) * DIMD + kbase + kq * 4;
    const int niter = KC / BK;
#pragma unroll 1
    for (int t = 0; t < niter; ++t) {
        const size_t ko = (size_t)t * BK;
        const float4 av0 = *(const float4*)(Z + offA0 + ko);
        const float4 av1 = *(const float4*)(Z + offA1 + ko);
        const float4 bv0 = *(const float4*)(Y + offA0 + ko);
        const float4 bv1 = *(const float4*)(Y + offA1 + ko);
        a2s0 += av0.x*av0.x + av0.y*av0.y + av0.z*av0.z + av0.w*av0.w;
        a2s1 += av1.x*av1.x + av1.y*av1.y + av1.z*av1.z + av1.w*av1.w;
        b2s0 += bv0.x*bv0.x + bv0.y*bv0.y + bv0.z*bv0.z + bv0.w*bv0.w;
        b2s1 += bv1.x*bv1.x + bv1.y*bv1.y + bv1.z*bv1.z + bv1.w*bv1.w;
        __syncthreads();
        const int kk = kq * 4;
        lA[kk+0][rowm]    = av0.x; lA[kk+1][rowm]    = av0.y;
        lA[kk+2][rowm]    = av0.z; lA[kk+3][rowm]    = av0.w;
        lA[kk+0][rowm+64] = av1.x; lA[kk+1][rowm+64] = av1.y;
        lA[kk+2][rowm+64] = av1.z; lA[kk+3][rowm+64] = av1.w;
        lB[kk+0][rowm]    = bv0.x; lB[kk+1][rowm]    = bv0.y;
        lB[kk+2][rowm]    = bv0.z; lB[kk+3][rowm]    = bv0.w;
        lB[kk+0][rowm+64] = bv1.x; lB[kk+1][rowm+64] = bv1.y;
        lB[kk+2][rowm+64] = bv1.z; lB[kk+3][rowm+64] = bv1.w;
        __syncthreads();
#pragma unroll
        for (int k = 0; k < BK; ++k) {
            const float4 a0 = *(const float4*)&lA[k][r0];
            const float4 a1 = *(const float4*)&lA[k][r0 + 4];
            const float4 b0 = *(const float4*)&lB[k][c0];
            const float4 b1 = *(const float4*)&lB[k][c0 + 4];
            const float a[8] = {a0.x,a0.y,a0.z,a0.w,a1.x,a1.y,a1.z,a1.w};
            const float b[8] = {b0.x,b0.y,b0.z,b0.w,b1.x,b1.y,b1.z,b1.w};
#pragma unroll
            for (int i = 0; i < 8; ++i)
#pragma unroll
                for (int j = 0; j < 8; ++j)
                    acc[i][j] = fmaf(a[i], b[j], acc[i][j]);
        }
    }
    __syncthreads();
    float* nrm = &lA[0][0];
    nrm[tid] = 0.f;
    __syncthreads();
    atomicAdd(&nrm[rowm],            a2s0);
    atomicAdd(&nrm[rowm + 64],       a2s1);
    atomicAdd(&nrm[128 + rowm],      b2s0);
    atomicAdd(&nrm[128 + rowm + 64], b2s1);
    __syncthreads();
    atomicAdd(&norms[tid], nrm[tid]);
#pragma unroll
    for (int i = 0; i < 8; ++i)
#pragma unroll
        for (int j = 0; j < 8; ++j)
            atomicAdd(&dots[(size_t)(r0 + i) * 128 + (c0 + j)], acc[i][j]);
}

// ---------------- reduce stage 1: nb partials -> 32 chunk-sums ---------------
__global__ __launch_bounds__(256)
void reduce_stage1(const float* __restrict__ partials, float* __restrict__ stage,
                   int per_chunk) {
    const int g = blockIdx.x * 256 + threadIdx.x;   // 512 blocks -> 131072
    const int f4 = g & 4095;
    const int chunk = g >> 12;
    const float4* p = (const float4*)partials;
    float4 s = make_float4(0.f, 0.f, 0.f, 0.f);
    const size_t base = (size_t)chunk * per_chunk;
    for (int k = 0; k < per_chunk; ++k) {
        const float4 v = p[(base + k) * 4096 + f4];
        s.x += v.x; s.y += v.y; s.z += v.z; s.w += v.w;
    }
    ((float4*)stage)[(size_t)chunk * 4096 + f4] = s;
}

// ---------------- rank: fused chunk-sum + sim + top1/top10 -------------------
// block a = sim row (Y index), thread b = col (Z index). out must be pre-zeroed.
__global__ __launch_bounds__(128)
void rank_kernel(const float* __restrict__ stage, const float* __restrict__ norms,
                 float* __restrict__ out, int nchunks) {
    __shared__ float sim[128];
    __shared__ int cnt;
    const int a = blockIdx.x;
    const int b = threadIdx.x;
    float s = 0.f;
    for (int c = 0; c < nchunks; ++c)
        s += stage[(size_t)c * 16384 + (size_t)b * 128 + a];
    const float v = s / fmaxf(sqrtf(norms[b]) * sqrtf(norms[128 + a]), 1e-8f);
    sim[b] = v;
    if (b == 0) cnt = 0;
    __syncthreads();
    const float diag = sim[a];
    if (b != a && v > diag) atomicAdd(&cnt, 1);
    __syncthreads();
    if (b == 0) {
        if (cnt == 0) atomicAdd(&out[0], 1.0f / 128.0f);   // k/128 exact in fp32
        if (cnt < 10) atomicAdd(&out[1], 1.0f / 128.0f);
    }
}

extern "C" void kernel_launch(void* const* d_in, const int* in_sizes, int n_in,
                              void* d_out, int out_size, void* d_ws, size_t ws_size,
                              hipStream_t stream) {
    const float* Z = (const float*)d_in[0];
    const float* Y = (const float*)d_in[1];
    float* dots     = (float*)d_ws;            // 16384 (fallback only)
    float* norms    = dots + 128 * 128;        // 256
    float* stage    = norms + 256;             // 32*16384
    float* partials = stage + 32 * 16384;      // nb*16384
    float* out      = (float*)d_out;

    const size_t head_floats = 128 * 128 + 256 + 32 * 16384;
    int nb = 0;
    const int cands[2] = {512, 256};
    for (int c = 0; c < 2; ++c) {
        if ((head_floats + (size_t)cands[c] * 16384) * sizeof(float) <= ws_size) {
            nb = cands[c];
            break;
        }
    }

    hipMemsetAsync(d_ws, 0, (128 * 128 + 256) * sizeof(float), stream);
    hipMemsetAsync(d_out, 0, 2 * sizeof(float), stream);

    if (nb > 0) {
        mfma_dot_kernel<<<nb, 512, 0, stream>>>(Z, Y, partials, norms,
                                                DIMD / nb / 32);
        reduce_stage1<<<512, 256, 0, stream>>>(partials, stage, nb / 32);
        rank_kernel<<<128, 128, 0, stream>>>(stage, norms, out, 32);
    } else {
        dot_norm_atomic<<<512, 256, 0, stream>>>(Z, Y, dots, norms, DIMD / 512);
        rank_kernel<<<128, 128, 0, stream>>>(dots, norms, out, 1);
    }
}